// Round 1
// baseline (1568.839 us; speedup 1.0000x reference)
//
#include <hip/hip_runtime.h>
#include <hip/hip_bf16.h>
#include <stdint.h>

using u16 = unsigned short;
typedef float floatx4 __attribute__((ext_vector_type(4)));
typedef __bf16 bfv8 __attribute__((ext_vector_type(8)));

#define AS1 __attribute__((address_space(1)))
#define AS3 __attribute__((address_space(3)))

__device__ __forceinline__ u16 f2bf_bits(float f) {
    __hip_bfloat16 h = __float2bfloat16(f);
    u16 u;
    __builtin_memcpy(&u, &h, 2);
    return u;
}
__device__ __forceinline__ float bf_bits2f(u16 u) {
    __hip_bfloat16 h;
    __builtin_memcpy(&h, &u, 2);
    return __bfloat162float(h);
}
__device__ __forceinline__ void gload_lds16(const void* g, void* l) {
    __builtin_amdgcn_global_load_lds((AS1 void*)(uintptr_t)g, (AS3 void*)l, 16, 0, 0);
}

// ---------------- cast fp32 -> bf16, 4 elems/thread ----------------
__global__ void cast_bf16_kernel(const float* __restrict__ in, u16* __restrict__ out, int n4) {
    int i = blockIdx.x * blockDim.x + threadIdx.x;
    if (i >= n4) return;
    float4 v = ((const float4*)in)[i];
    ushort4 o;
    o.x = f2bf_bits(v.x); o.y = f2bf_bits(v.y); o.z = f2bf_bits(v.z); o.w = f2bf_bits(v.w);
    ((ushort4*)out)[i] = o;
}

// ---------------- transpose+cast fp32 [z][R][C] -> bf16 [z][C][R] ----------------
__global__ void transpose_cast_kernel(const float* __restrict__ src, u16* __restrict__ dst,
                                      int R, int C, long sSrc, long sDst) {
    __shared__ float tile[32][33];
    const float* s = src + (long)blockIdx.z * sSrc;
    u16* d = dst + (long)blockIdx.z * sDst;
    int c0 = blockIdx.x * 32, r0 = blockIdx.y * 32;
    int tx = threadIdx.x, ty = threadIdx.y;
    #pragma unroll
    for (int i = 0; i < 4; i++)
        tile[ty + 8*i][tx] = s[(long)(r0 + ty + 8*i) * C + c0 + tx];
    __syncthreads();
    #pragma unroll
    for (int i = 0; i < 4; i++)
        d[(long)(c0 + ty + 8*i) * R + r0 + tx] = f2bf_bits(tile[tx][ty + 8*i]);
}

// ---------------- transpose V [4096][512]bf16 -> VT [16][128][1024]bf16 ----------------
__global__ void transpose_v_kernel(const u16* __restrict__ V, u16* __restrict__ VT) {
    __shared__ u16 tile[32][33];
    int z = blockIdx.z, b = z >> 2, h = z & 3;
    int s0 = blockIdx.x * 32, d0 = blockIdx.y * 32;
    int tx = threadIdx.x, ty = threadIdx.y;
    #pragma unroll
    for (int i = 0; i < 4; i++)
        tile[ty + 8*i][tx] = V[(long)(b*1024 + s0 + ty + 8*i) * 512 + h*128 + d0 + tx];
    __syncthreads();
    #pragma unroll
    for (int i = 0; i < 4; i++)
        VT[((long)z*128 + d0 + ty + 8*i) * 1024 + s0 + tx] = tile[tx][ty + 8*i];
}

// ---------------- pack bq/bk/bv -> PB[3][8][512] ----------------
__global__ void pack_bias_kernel(const float* __restrict__ bq, const float* __restrict__ bk,
                                 const float* __restrict__ bv, float* __restrict__ pb) {
    int i = blockIdx.x * 256 + threadIdx.x;  // 0..4095
    const float* s = blockIdx.y == 0 ? bq : (blockIdx.y == 1 ? bk : bv);
    pb[blockIdx.y * 4096 + i] = s[i];
}

// ---------------- router: logits + Scale-and-Fire routing weights ----------------
__global__ __launch_bounds__(512)
void router_kernel(const float* __restrict__ x, const float* __restrict__ gw,
                   const float* __restrict__ gb, float* __restrict__ rw,
                   float* __restrict__ logits_out) {
    int row = blockIdx.x;
    int w = threadIdx.x >> 6;     // expert 0..7
    int lane = threadIdx.x & 63;
    const float* xr = x + (long)row * 512;
    float sum = 0.f;
    #pragma unroll
    for (int i = 0; i < 8; i++) {
        int d = lane + 64 * i;
        sum += xr[d] * gw[d * 8 + w];
    }
    #pragma unroll
    for (int o = 32; o; o >>= 1) sum += __shfl_down(sum, o, 64);
    __shared__ float lg[8];
    if (lane == 0) lg[w] = sum + gb[w];
    __syncthreads();
    if (threadIdx.x == 0) {
        float l[8];
        #pragma unroll
        for (int e = 0; e < 8; e++) l[e] = lg[e];
        int i1 = 0;
        for (int e = 1; e < 8; e++) if (l[e] > l[i1]) i1 = e;
        int i2 = -1;
        for (int e = 0; e < 8; e++) { if (e == i1) continue; if (i2 < 0 || l[e] > l[i2]) i2 = e; }
        for (int e = 0; e < 8; e++) {
            float v = (e == i1 || e == i2) ? (l[e] > 0.f ? l[e] : 0.f) : 0.f;
            float r = 0.f, mem = v;
            #pragma unroll
            for (int lvl = 0; lvl < 4; lvl++) {
                float thr = 4.0f / (float)(1 << lvl);
                if (mem >= thr) { r += thr; mem -= thr; }
            }
            rw[(long)row * 8 + e] = r;
            logits_out[(long)row * 8 + e] = l[e];
        }
    }
}

// ---------------- GEMM: C[M,N] = A[M,K] @ Bt[N,K]^T (+bias)(relu)(alpha), m97 structure ----------------
template<bool BIAS, bool RELU, bool SCALE, typename OUT>
__global__ __launch_bounds__(256)
void gemm_kernel(const u16* __restrict__ A, int lda, long sAo, long sAi,
                 const u16* __restrict__ B, int ldb, long sBo, long sBi,
                 OUT* __restrict__ C, int ldc, long sCo, long sCi,
                 const float* __restrict__ bias, long sBiasO, long sBiasI,
                 int zdiv, float alpha, int K) {
    __shared__ __align__(16) u16 As[128 * 32];
    __shared__ __align__(16) u16 Bs[128 * 32];
    const int z = blockIdx.z;
    const int zo = z / zdiv, zi = z % zdiv;
    const u16* Ab = A + zo * sAo + zi * sAi + (long)blockIdx.y * 128 * lda;
    const u16* Bb = B + zo * sBo + zi * sBi + (long)blockIdx.x * 128 * ldb;

    const int tid = threadIdx.x;
    const int w = tid >> 6, lane = tid & 63;
    const int wy = w >> 1, wx = w & 1;
    const int lr = lane >> 2, lp = lane & 3;
    const int quad = lane >> 4, mrow = lane & 15;

    floatx4 acc[4][4];
    #pragma unroll
    for (int i = 0; i < 4; i++)
        #pragma unroll
        for (int j = 0; j < 4; j++)
            acc[i][j] = floatx4{0.f, 0.f, 0.f, 0.f};

    for (int k0 = 0; k0 < K; k0 += 32) {
        #pragma unroll
        for (int j = 0; j < 2; j++) {
            const int s = w * 2 + j;
            const int r = s * 16 + lr;
            const int c = lp ^ ((r >> 1) & 3);   // XOR swizzle (16B chunks)
            gload_lds16(Ab + (long)r * lda + k0 + c * 8, As + s * 512);
            gload_lds16(Bb + (long)r * ldb + k0 + c * 8, Bs + s * 512);
        }
        __syncthreads();
        bfv8 af[4], bfr[4];
        #pragma unroll
        for (int mi = 0; mi < 4; mi++) {
            const int r = wy * 64 + mi * 16 + mrow;
            const int p = quad ^ ((r >> 1) & 3);
            af[mi] = *(const bfv8*)&As[r * 32 + p * 8];
        }
        #pragma unroll
        for (int ni = 0; ni < 4; ni++) {
            const int r = wx * 64 + ni * 16 + mrow;
            const int p = quad ^ ((r >> 1) & 3);
            bfr[ni] = *(const bfv8*)&Bs[r * 32 + p * 8];
        }
        #pragma unroll
        for (int mi = 0; mi < 4; mi++)
            #pragma unroll
            for (int ni = 0; ni < 4; ni++)
                acc[mi][ni] = __builtin_amdgcn_mfma_f32_16x16x32_bf16(af[mi], bfr[ni], acc[mi][ni], 0, 0, 0);
        __syncthreads();
    }

    OUT* Cb = C + zo * sCo + zi * sCi + (long)blockIdx.y * 128 * ldc + (long)blockIdx.x * 128;
    const float* biasb = BIAS ? (bias + zo * sBiasO + zi * sBiasI + (long)blockIdx.x * 128) : nullptr;
    #pragma unroll
    for (int ni = 0; ni < 4; ni++) {
        const int col = wx * 64 + ni * 16 + mrow;
        float bv = 0.f;
        if (BIAS) bv = biasb[col];
        #pragma unroll
        for (int mi = 0; mi < 4; mi++) {
            #pragma unroll
            for (int r = 0; r < 4; r++) {
                const int row = wy * 64 + mi * 16 + quad * 4 + r;
                float v = acc[mi][ni][r];
                if (SCALE) v *= alpha;
                if (BIAS) v += bv;
                if (RELU) v = fmaxf(v, 0.f);
                if constexpr (sizeof(OUT) == 2)
                    ((u16*)Cb)[(long)row * ldc + col] = f2bf_bits(v);
                else
                    ((float*)Cb)[(long)row * ldc + col] = v;
            }
        }
    }
}

// ---------------- softmax over rows of 1024, in-place on bf16 ----------------
__global__ __launch_bounds__(256)
void softmax_kernel(u16* __restrict__ S) {
    long row = blockIdx.x;
    u16* p = S + row * 1024;
    int t = threadIdx.x, w = t >> 6, lane = t & 63;
    float v[4];
    float mx = -1e30f;
    #pragma unroll
    for (int i = 0; i < 4; i++) {
        v[i] = bf_bits2f(p[t + 256 * i]);
        mx = fmaxf(mx, v[i]);
    }
    #pragma unroll
    for (int o = 32; o; o >>= 1) mx = fmaxf(mx, __shfl_down(mx, o, 64));
    __shared__ float red[8];
    if (lane == 0) red[w] = mx;
    __syncthreads();
    mx = fmaxf(fmaxf(red[0], red[1]), fmaxf(red[2], red[3]));
    float sum = 0.f;
    #pragma unroll
    for (int i = 0; i < 4; i++) { v[i] = __expf(v[i] - mx); sum += v[i]; }
    #pragma unroll
    for (int o = 32; o; o >>= 1) sum += __shfl_down(sum, o, 64);
    if (lane == 0) red[4 + w] = sum;
    __syncthreads();
    float inv = 1.f / (red[4] + red[5] + red[6] + red[7]);
    #pragma unroll
    for (int i = 0; i < 4; i++) p[t + 256 * i] = f2bf_bits(v[i] * inv);
}

// ---------------- LN1: h = LN(x + t), write fp32 + bf16 ----------------
__global__ __launch_bounds__(128)
void ln1_kernel(const float* __restrict__ x, const float* __restrict__ t,
                const float* __restrict__ s, const float* __restrict__ b,
                float* __restrict__ hf, u16* __restrict__ hb) {
    long row = blockIdx.x;
    int tid = threadIdx.x, w = tid >> 6, lane = tid & 63;
    float4 xv = *(const float4*)(x + row * 512 + tid * 4);
    float4 tv = *(const float4*)(t + row * 512 + tid * 4);
    float v[4] = {xv.x + tv.x, xv.y + tv.y, xv.z + tv.z, xv.w + tv.w};
    float sum = v[0] + v[1] + v[2] + v[3];
    #pragma unroll
    for (int o = 32; o; o >>= 1) sum += __shfl_down(sum, o, 64);
    __shared__ float sh[4];
    if (lane == 0) sh[w] = sum;
    __syncthreads();
    float mu = (sh[0] + sh[1]) * (1.f / 512.f);
    float sq = 0.f;
    #pragma unroll
    for (int j = 0; j < 4; j++) { float d = v[j] - mu; sq += d * d; }
    #pragma unroll
    for (int o = 32; o; o >>= 1) sq += __shfl_down(sq, o, 64);
    if (lane == 0) sh[2 + w] = sq;
    __syncthreads();
    float inv = 1.f / sqrtf((sh[2] + sh[3]) * (1.f / 512.f) + 1e-5f);
    float4 sv = *(const float4*)(s + tid * 4);
    float4 bv = *(const float4*)(b + tid * 4);
    float o0 = (v[0] - mu) * inv * sv.x + bv.x;
    float o1 = (v[1] - mu) * inv * sv.y + bv.y;
    float o2 = (v[2] - mu) * inv * sv.z + bv.z;
    float o3 = (v[3] - mu) * inv * sv.w + bv.w;
    *(float4*)(hf + row * 512 + tid * 4) = make_float4(o0, o1, o2, o3);
    ushort4 ub;
    ub.x = f2bf_bits(o0); ub.y = f2bf_bits(o1); ub.z = f2bf_bits(o2); ub.w = f2bf_bits(o3);
    *(ushort4*)(hb + row * 512 + tid * 4) = ub;
}

// ---------------- LN2 + weighted accumulate into d_out ----------------
__global__ __launch_bounds__(128)
void ln2acc_kernel(const float* __restrict__ hf, const float* __restrict__ t,
                   const float* __restrict__ s, const float* __restrict__ b,
                   const float* __restrict__ rw, int e, float* __restrict__ out) {
    long row = blockIdx.x;
    float wgt = rw[row * 8 + e];
    if (wgt == 0.f) return;   // uniform per block
    int tid = threadIdx.x, w = tid >> 6, lane = tid & 63;
    float4 xv = *(const float4*)(hf + row * 512 + tid * 4);
    float4 tv = *(const float4*)(t + row * 512 + tid * 4);
    float v[4] = {xv.x + tv.x, xv.y + tv.y, xv.z + tv.z, xv.w + tv.w};
    float sum = v[0] + v[1] + v[2] + v[3];
    #pragma unroll
    for (int o = 32; o; o >>= 1) sum += __shfl_down(sum, o, 64);
    __shared__ float sh[4];
    if (lane == 0) sh[w] = sum;
    __syncthreads();
    float mu = (sh[0] + sh[1]) * (1.f / 512.f);
    float sq = 0.f;
    #pragma unroll
    for (int j = 0; j < 4; j++) { float d = v[j] - mu; sq += d * d; }
    #pragma unroll
    for (int o = 32; o; o >>= 1) sq += __shfl_down(sq, o, 64);
    if (lane == 0) sh[2 + w] = sq;
    __syncthreads();
    float inv = 1.f / sqrtf((sh[2] + sh[3]) * (1.f / 512.f) + 1e-5f);
    float4 sv = *(const float4*)(s + tid * 4);
    float4 bv = *(const float4*)(b + tid * 4);
    float4 cur = *(float4*)(out + row * 512 + tid * 4);
    cur.x += wgt * ((v[0] - mu) * inv * sv.x + bv.x);
    cur.y += wgt * ((v[1] - mu) * inv * sv.y + bv.y);
    cur.z += wgt * ((v[2] - mu) * inv * sv.z + bv.z);
    cur.w += wgt * ((v[3] - mu) * inv * sv.w + bv.w);
    *(float4*)(out + row * 512 + tid * 4) = cur;
}

// ---------------- workspace layout (bytes) ----------------
static const size_t OFF_XB  = 0;                                  // bf16 [4096][512]
static const size_t OFF_WB  = OFF_XB  + (size_t)4096*512*2;       // bf16, all transposed weights
static const size_t OFF_RW  = OFF_WB  + (size_t)25165824*2;       // f32 [4096][8]
static const size_t OFF_PB  = OFF_RW  + (size_t)4096*8*4;         // f32 [3][8][512]
static const size_t OFF_QKV = OFF_PB  + (size_t)3*8*512*4;        // bf16 [3][4096][512]
static const size_t OFF_VT  = OFF_QKV + (size_t)3*4096*512*2;     // bf16 [16][128][1024]
static const size_t OFF_S   = OFF_VT  + (size_t)16*128*1024*2;    // bf16 [16][1024][1024]
static const size_t OFF_O   = OFF_S   + (size_t)16*1024*1024*2;   // bf16 [4096][512]
static const size_t OFF_T   = OFF_O   + (size_t)4096*512*2;       // f32  [4096][512]
static const size_t OFF_HF  = OFF_T   + (size_t)4096*512*4;       // f32  [4096][512]
static const size_t OFF_HB  = OFF_HF  + (size_t)4096*512*4;       // bf16 [4096][512]
static const size_t OFF_MID = OFF_HB  + (size_t)4096*512*2;       // bf16 [4096][2048]

extern "C" void kernel_launch(void* const* d_in, const int* in_sizes, int n_in,
                              void* d_out, int out_size, void* d_ws, size_t ws_size,
                              hipStream_t stream) {
    const float* x      = (const float*)d_in[0];
    const float* gate_w = (const float*)d_in[1];
    const float* gate_b = (const float*)d_in[2];
    const float* ln1_s  = (const float*)d_in[3];
    const float* ln1_b  = (const float*)d_in[4];
    const float* ln2_s  = (const float*)d_in[5];
    const float* ln2_b  = (const float*)d_in[6];
    const float* wq = (const float*)d_in[7];
    const float* wk = (const float*)d_in[8];
    const float* wv = (const float*)d_in[9];
    const float* wo = (const float*)d_in[10];
    const float* bo = (const float*)d_in[14];
    const float* w1 = (const float*)d_in[15];
    const float* b1 = (const float*)d_in[16];
    const float* w2 = (const float*)d_in[17];
    const float* b2 = (const float*)d_in[18];
    float* out = (float*)d_out;

    char* ws = (char*)d_ws;
    u16*   XB  = (u16*)(ws + OFF_XB);
    u16*   WB  = (u16*)(ws + OFF_WB);
    float* RW  = (float*)(ws + OFF_RW);
    float* PB  = (float*)(ws + OFF_PB);
    u16*   QKV = (u16*)(ws + OFF_QKV);
    u16*   VT  = (u16*)(ws + OFF_VT);
    u16*   S   = (u16*)(ws + OFF_S);
    u16*   O   = (u16*)(ws + OFF_O);
    float* T   = (float*)(ws + OFF_T);
    float* HF  = (float*)(ws + OFF_HF);
    u16*   HB  = (u16*)(ws + OFF_HB);
    u16*   MID = (u16*)(ws + OFF_MID);

    hipMemsetAsync(d_out, 0, (size_t)4096 * 512 * 4, stream);

    cast_bf16_kernel<<<dim3(2048), 256, 0, stream>>>(x, XB, 4096 * 512 / 4);
    transpose_cast_kernel<<<dim3(16,16,8), dim3(32,8), 0, stream>>>(wq, WB + 0,        512,  512,  262144,  262144);
    transpose_cast_kernel<<<dim3(16,16,8), dim3(32,8), 0, stream>>>(wk, WB + 2097152,  512,  512,  262144,  262144);
    transpose_cast_kernel<<<dim3(16,16,8), dim3(32,8), 0, stream>>>(wv, WB + 4194304,  512,  512,  262144,  262144);
    transpose_cast_kernel<<<dim3(16,16,8), dim3(32,8), 0, stream>>>(wo, WB + 6291456,  512,  512,  262144,  262144);
    transpose_cast_kernel<<<dim3(64,16,8), dim3(32,8), 0, stream>>>(w1, WB + 8388608,  512,  2048, 1048576, 1048576);
    transpose_cast_kernel<<<dim3(16,64,8), dim3(32,8), 0, stream>>>(w2, WB + 16777216, 2048, 512,  1048576, 1048576);
    pack_bias_kernel<<<dim3(16,3), 256, 0, stream>>>((const float*)d_in[11], (const float*)d_in[12],
                                                     (const float*)d_in[13], PB);
    router_kernel<<<4096, 512, 0, stream>>>(x, gate_w, gate_b, RW, out + 2097152);

    const float isq = 0.08838834764831845f;  // 1/sqrt(128)

    for (int e = 0; e < 8; e++) {
        // QKV projection: z = 0,1,2 -> Q,K,V
        gemm_kernel<true,false,false,u16><<<dim3(4,32,3), 256, 0, stream>>>(
            XB, 512, 0, 0,
            WB + (size_t)e*262144, 512, 2097152, 0,
            QKV, 512, 2097152, 0,
            PB + e*512, 4096, 0,
            1, 1.f, 512);
        // scores = Q K^T / sqrt(dh), z=(b,h)
        gemm_kernel<false,false,true,u16><<<dim3(8,8,16), 256, 0, stream>>>(
            QKV, 512, 524288, 128,
            QKV + 2097152, 512, 524288, 128,
            S, 1024, 4194304, 1048576,
            nullptr, 0, 0,
            4, isq, 128);
        softmax_kernel<<<16384, 256, 0, stream>>>(S);
        transpose_v_kernel<<<dim3(32,4,16), dim3(32,8), 0, stream>>>(QKV + 2*2097152, VT);
        // O = P V
        gemm_kernel<false,false,false,u16><<<dim3(1,8,16), 256, 0, stream>>>(
            S, 1024, 4194304, 1048576,
            VT, 1024, 524288, 131072,
            O, 512, 524288, 128,
            nullptr, 0, 0,
            4, 1.f, 1024);
        // Wo projection -> T (fp32)
        gemm_kernel<true,false,false,float><<<dim3(4,32,1), 256, 0, stream>>>(
            O, 512, 0, 0,
            WB + 6291456 + (size_t)e*262144, 512, 0, 0,
            T, 512, 0, 0,
            bo + e*512, 0, 0,
            1, 1.f, 512);
        ln1_kernel<<<4096, 128, 0, stream>>>(x, T, ln1_s + e*512, ln1_b + e*512, HF, HB);
        // FFN1 + relu -> MID (bf16)
        gemm_kernel<true,true,false,u16><<<dim3(16,32,1), 256, 0, stream>>>(
            HB, 512, 0, 0,
            WB + 8388608 + (size_t)e*1048576, 512, 0, 0,
            MID, 2048, 0, 0,
            b1 + e*2048, 0, 0,
            1, 1.f, 512);
        // FFN2 -> T (fp32)
        gemm_kernel<true,false,false,float><<<dim3(4,32,1), 256, 0, stream>>>(
            MID, 2048, 0, 0,
            WB + 16777216 + (size_t)e*1048576, 2048, 0, 0,
            T, 512, 0, 0,
            b2 + e*512, 0, 0,
            1, 1.f, 2048);
        ln2acc_kernel<<<4096, 128, 0, stream>>>(HF, T, ln2_s + e*512, ln2_b + e*512, RW, e, out);
    }
}